// Round 7
// baseline (393.309 us; speedup 1.0000x reference)
//
#include <hip/hip_runtime.h>
#include <hip/hip_bf16.h>

#define T    4
#define C    256
#define H    48
#define W    48
#define HW   2304
#define OFFC 200
#define CK5  6400      // offset/deform K, (q,c) c-inner
#define CK9  2304      // temporal per-tap K, (j,c) c-inner
#define NFULL 9216     // T*HW
#define BPAD 72        // B LDS row pitch (shorts)

typedef __attribute__((ext_vector_type(8))) short bf16x8;
typedef __attribute__((ext_vector_type(4))) float f32x4;

__device__ __forceinline__ unsigned short f2bf(float f) {
    unsigned int u = __float_as_uint(f);
    return (unsigned short)((u + 0x7FFFu + ((u >> 16) & 1u)) >> 16);
}
__device__ __forceinline__ float bflo(unsigned int v) { return __uint_as_float(v << 16); }
__device__ __forceinline__ float bfhi(unsigned int v) { return __uint_as_float(v & 0xFFFF0000u); }
__device__ __forceinline__ unsigned int pack2(float lo, float hi) {
    __hip_bfloat162 h = __float22bfloat162_rn(make_float2(lo, hi));
    return *reinterpret_cast<unsigned int*>(&h);
}

// ---------------------------------------------------------------------------
// prep: all weight casts + offb zero + out bias-fill in ONE launch.
// grid 24320 x 256.
// ---------------------------------------------------------------------------
__global__ __launch_bounds__(256) void prep_k(const float* __restrict__ w_off,
                                              const float* __restrict__ w_def,
                                              const float* __restrict__ w_temp,
                                              const float* __restrict__ bias,
                                              unsigned short* __restrict__ wbo,
                                              unsigned short* __restrict__ wbd,
                                              unsigned short* __restrict__ wbT,
                                              float* __restrict__ offb,
                                              float* __restrict__ out) {
    long i = (long)blockIdx.x * 256 + threadIdx.x;
    if (i < 1638400) {                       // w_off -> wbo (M padded to 256)
        const int c = (int)(i & 255); const int rest = (int)(i >> 8);
        const int q = rest % 25, o = rest / 25;
        wbo[(long)o * CK5 + q * 256 + c] =
            (o < OFFC) ? f2bf(w_off[((long)o * 256 + c) * 25 + q]) : (unsigned short)0;
    } else if (i < 3276800) {                // w_def -> wbd
        i -= 1638400;
        const int c = (int)(i & 255); const int rest = (int)(i >> 8);
        const int q = rest % 25, o = rest / 25;
        wbd[(long)o * CK5 + q * 256 + c] = f2bf(w_def[((long)o * 256 + c) * 25 + q]);
    } else if (i < 5046272) {                // w_temp -> wbT[kt][o][(j,c)]
        i -= 3276800;
        const int c = (int)(i & 255); const int rest = (int)(i >> 8);
        const int j = rest % 9, oo = rest / 9;
        const int o = oo & 255, kt = oo >> 8;
        wbT[(long)kt * (256 * CK9) + (long)o * CK9 + j * 256 + c] =
            f2bf(w_temp[((long)o * 256 + c) * 27 + kt * 9 + j]);
    } else if (i < 5636096) {                // zero offb
        i -= 5046272;
        ((float4*)offb)[i] = make_float4(0.f, 0.f, 0.f, 0.f);
    } else {                                 // out = bias
        i -= 5636096;
        const float b = bias[(int)(i / 2304)];
        ((float4*)out)[i] = make_float4(b, b, b, b);
    }
}

// ---------------------------------------------------------------------------
// x[c][t][p] fp32 -> xt[t][p][c] bf16 via LDS transpose. grid (36, 4 ct, T)
// ---------------------------------------------------------------------------
__global__ __launch_bounds__(256) void xt_k(const float* __restrict__ x,
                                            unsigned short* __restrict__ xt) {
    __shared__ float tile[64][65];
    const int p0 = blockIdx.x * 64, c0 = blockIdx.y * 64, t = blockIdx.z;
    const int px = threadIdx.x & 63, sub = threadIdx.x >> 6;
    for (int cl = sub; cl < 64; cl += 4)
        tile[px][cl] = x[((long)(c0 + cl) * T + t) * HW + p0 + px];
    __syncthreads();
    const int seg = sub * 16;
    unsigned int pk[8];
    #pragma unroll
    for (int d = 0; d < 8; ++d)
        pk[d] = pack2(tile[px][seg + d * 2], tile[px][seg + d * 2 + 1]);
    unsigned short* orow = xt + ((long)t * HW + p0 + px) * 256 + c0 + seg;
    *(uint4*)(orow + 0) = make_uint4(pk[0], pk[1], pk[2], pk[3]);
    *(uint4*)(orow + 8) = make_uint4(pk[4], pk[5], pk[6], pk[7]);
}

// ---------------------------------------------------------------------------
// Shared MFMA core (BM=256, BN=64, BK=64).  A direct from global (16B frags,
// L2-resident weights), B from LDS dbuf (pitch 72).
// ---------------------------------------------------------------------------
__device__ __forceinline__ void mfma_64k(const unsigned short* __restrict__ Abase,
                                         long ldA, int kk,
                                         const unsigned short* __restrict__ Bcur,
                                         int quad, int l16, f32x4 acc[4][4]) {
    #pragma unroll
    for (int kh = 0; kh < 2; ++kh) {
        bf16x8 af[4], bfr[4];
        const unsigned short* Ak = Abase + kk + kh * 32;
        #pragma unroll
        for (int i4 = 0; i4 < 4; ++i4)
            af[i4] = *(const bf16x8*)(Ak + (long)(i4 * 16) * ldA);
        #pragma unroll
        for (int j = 0; j < 4; ++j)
            bfr[j] = *(const bf16x8*)(Bcur + (j * 16 + l16) * BPAD + kh * 32 + quad * 8);
        #pragma unroll
        for (int i4 = 0; i4 < 4; ++i4)
            #pragma unroll
            for (int j = 0; j < 4; ++j)
                acc[i4][j] = __builtin_amdgcn_mfma_f32_16x16x32_bf16(af[i4], bfr[j], acc[i4][j], 0, 0, 0);
    }
}
__device__ __forceinline__ void epilogue_atomic(float* __restrict__ Cf, int n0,
                                                int wave, int quad, int l16,
                                                int Mvalid, f32x4 acc[4][4]) {
    #pragma unroll
    for (int i = 0; i < 4; ++i)
        #pragma unroll
        for (int rr = 0; rr < 4; ++rr) {
            const int o = wave * 64 + i * 16 + quad * 4 + rr;
            if (o >= Mvalid) continue;
            #pragma unroll
            for (int j = 0; j < 4; ++j)
                unsafeAtomicAdd(Cf + (long)o * NFULL + n0 + j * 16 + l16, acc[i][j][rr]);
        }
}

// ---------------------------------------------------------------------------
// Shift-window GEMM body (offset conv: mode 0, 5x5 pad2; temporal: mode 1,
// 3x3 pad1).  Single barrier per iter, dbuf B.
// ---------------------------------------------------------------------------
__device__ __forceinline__ void gemm_shift_body(unsigned short (*Bsl)[64 * BPAD],
                                                const unsigned short* __restrict__ A, long ldA,
                                                const unsigned short* __restrict__ xt, int tsrc,
                                                float* __restrict__ Cf, int Mvalid,
                                                int n0, int k0, int iters, int mode) {
    const int tid = threadIdx.x;
    const int wave = tid >> 6, lane = tid & 63;
    const int quad = lane >> 4, l16 = lane & 15;
    const int t = n0 / HW, p0 = n0 - t * HW;
    const int px = tid >> 2, seg = tid & 3;
    const int p = p0 + px, h = p / 48, w = p - h * 48;
    const unsigned short* xts = xt + (long)tsrc * HW * 256 + seg * 8;
    const unsigned short* Abase = A + (long)(wave * 64 + l16) * ldA + quad * 8;

    auto produce = [&](int kk, uint4& v0, uint4& v1) {
        const int q = kk >> 8, cb = kk & 255;
        int qy, qx;
        if (mode == 0) { const int d = q / 5; qy = d - 2; qx = q - d * 5 - 2; }
        else           { const int d = q / 3; qy = d - 1; qx = q - d * 3 - 1; }
        const int y = h + qy, xx = w + qx;
        v0 = make_uint4(0u, 0u, 0u, 0u); v1 = v0;
        if ((y >= 0) & (y < 48) & (xx >= 0) & (xx < 48)) {
            const unsigned short* bp = xts + (y * 48 + xx) * 256 + cb;
            v0 = *(const uint4*)bp; v1 = *(const uint4*)(bp + 32);
        }
    };

    {   uint4 c0, c1;
        produce(k0, c0, c1);
        *(uint4*)(&Bsl[0][px * BPAD + seg * 8])      = c0;
        *(uint4*)(&Bsl[0][px * BPAD + 32 + seg * 8]) = c1;
    }
    __syncthreads();

    f32x4 acc[4][4] = {};
    for (int i = 0; i < iters; ++i) {
        const int kk = k0 + i * 64;
        const bool more = (i + 1 < iters);
        uint4 nv0, nv1;
        if (more) produce(kk + 64, nv0, nv1);          // loads issue early
        mfma_64k(Abase, ldA, kk, Bsl[i & 1], quad, l16, acc);
        if (more) {
            unsigned short* Bn = Bsl[(i + 1) & 1];
            *(uint4*)(&Bn[px * BPAD + seg * 8])      = nv0;
            *(uint4*)(&Bn[px * BPAD + 32 + seg * 8]) = nv1;
        }
        __syncthreads();
    }
    epilogue_atomic(Cf, n0, wave, quad, l16, Mvalid, acc);
}

// offset (z 0..4, split-K 5) + temporal (z 5..10, tap*2+half) in ONE launch.
__global__ __launch_bounds__(256) void gemm_ot_k(const unsigned short* __restrict__ wbo,
                                                 const unsigned short* __restrict__ wbT,
                                                 const unsigned short* __restrict__ xt,
                                                 float* __restrict__ offb,
                                                 float* __restrict__ out) {
    __shared__ unsigned short Bsl[2][64 * BPAD];
    const int z = blockIdx.z, n0 = blockIdx.x * 64;
    const int t = n0 / HW;
    if (z < 5) {
        gemm_shift_body(Bsl, wbo, CK5, xt, t, offb, OFFC, n0, z * 1280, 20, 0);
    } else {
        const int zz = z - 5, kt = zz >> 1, half = zz & 1;
        const int tsrc = t + kt - 1;
        if (tsrc < 0 || tsrc >= T) return;
        gemm_shift_body(Bsl, wbT + (long)kt * 256 * CK9, CK9, xt, tsrc, out, C,
                        n0, half * 1152, 18, 1);
    }
}

// ---------------------------------------------------------------------------
// Deformable GEMM: B built by bilinear blend of xt rows; offsets prefetched
// one chunk ahead; corners loaded before MFMA, blended after.
// grid (144, 1, 5): split-K 5 (kLen 1280, 20 iters).
// ---------------------------------------------------------------------------
__device__ __forceinline__ void pos_calc(int h, int w, int q, float dy, float dx,
                                         float wgt[4], int idx[4]) {
    const int d = q / 5;
    const int qy = d - 2, qx = q - d * 5 - 2;
    const float sy = (float)(h + qy) + dy;
    const float sx = (float)(w + qx) + dx;
    const float y0f = floorf(sy), x0f = floorf(sx);
    const float wy = sy - y0f, wx = sx - x0f;
    const int y0 = (int)y0f, x0 = (int)x0f;
    const int y1 = y0 + 1, x1 = x0 + 1;
    float w00 = (1.f - wy) * (1.f - wx);
    float w01 = (1.f - wy) * wx;
    float w10 = wy * (1.f - wx);
    float w11 = wy * wx;
    const bool vy0 = (y0 >= 0) & (y0 < 48), vy1 = (y1 >= 0) & (y1 < 48);
    const bool vx0 = (x0 >= 0) & (x0 < 48), vx1 = (x1 >= 0) & (x1 < 48);
    if (!(vy0 & vx0)) w00 = 0.f;
    if (!(vy0 & vx1)) w01 = 0.f;
    if (!(vy1 & vx0)) w10 = 0.f;
    if (!(vy1 & vx1)) w11 = 0.f;
    const int yc0 = min(max(y0, 0), 47), yc1 = min(max(y1, 0), 47);
    const int xc0 = min(max(x0, 0), 47), xc1 = min(max(x1, 0), 47);
    wgt[0] = w00; wgt[1] = w01; wgt[2] = w10; wgt[3] = w11;
    idx[0] = yc0 * 48 + xc0; idx[1] = yc0 * 48 + xc1;
    idx[2] = yc1 * 48 + xc0; idx[3] = yc1 * 48 + xc1;
}
__device__ __forceinline__ uint4 blend4(const uint4 u[4], const float wgt[4]) {
    unsigned int pk[4];
    #pragma unroll
    for (int qi = 0; qi < 4; ++qi) {
        const unsigned int a = ((const unsigned int*)&u[0])[qi];
        const unsigned int b = ((const unsigned int*)&u[1])[qi];
        const unsigned int c = ((const unsigned int*)&u[2])[qi];
        const unsigned int d = ((const unsigned int*)&u[3])[qi];
        const float rl = wgt[0] * bflo(a) + wgt[1] * bflo(b) + wgt[2] * bflo(c) + wgt[3] * bflo(d);
        const float rh = wgt[0] * bfhi(a) + wgt[1] * bfhi(b) + wgt[2] * bfhi(c) + wgt[3] * bfhi(d);
        pk[qi] = pack2(rl, rh);
    }
    return make_uint4(pk[0], pk[1], pk[2], pk[3]);
}

__global__ __launch_bounds__(256) void gemm_def_k(const unsigned short* __restrict__ A,
                                                  const unsigned short* __restrict__ xt,
                                                  const float* __restrict__ offb,
                                                  float* __restrict__ Cf) {
    __shared__ unsigned short Bsl[2][64 * BPAD];
    const int tid = threadIdx.x;
    const int wave = tid >> 6, lane = tid & 63;
    const int quad = lane >> 4, l16 = lane & 15;
    const int n0 = blockIdx.x * 64, k0 = blockIdx.z * 1280;
    const int t = n0 / HW, p0 = n0 - t * HW;
    const int px = tid >> 2, seg = tid & 3;
    const int p = p0 + px, h = p / 48, w = p - h * 48;
    const int nabs = n0 + px;
    const unsigned short* xts = xt + (long)t * HW * 256 + seg * 8;
    const unsigned short* Abase = A + (long)(wave * 64 + l16) * CK5 + quad * 8;

    auto off_load = [&](int kk, float& dy, float& dx) {
        const int q = kk >> 8, g = (kk & 255) >> 6;
        dy = offb[(long)(g * 50 + 2 * q) * NFULL + nabs];
        dx = offb[(long)(g * 50 + 2 * q + 1) * NFULL + nabs];
    };
    auto corners = [&](int kk, float dy, float dx, uint4 u[8], float wgt[4]) {
        const int cb = kk & 255;
        int idx[4];
        pos_calc(h, w, kk >> 8, dy, dx, wgt, idx);
        #pragma unroll
        for (int cn = 0; cn < 4; ++cn) {
            const unsigned short* bp = xts + idx[cn] * 256 + cb;
            u[cn]     = *(const uint4*)bp;
            u[cn + 4] = *(const uint4*)(bp + 32);
        }
    };

    float dyN, dxN;
    {
        float dy0, dx0;
        off_load(k0, dy0, dx0);
        uint4 u[8]; float wg[4];
        corners(k0, dy0, dx0, u, wg);
        *(uint4*)(&Bsl[0][px * BPAD + seg * 8])      = blend4(u,     wg);
        *(uint4*)(&Bsl[0][px * BPAD + 32 + seg * 8]) = blend4(u + 4, wg);
        off_load(k0 + 64, dyN, dxN);
    }
    __syncthreads();

    f32x4 acc[4][4] = {};
    for (int i = 0; i < 20; ++i) {
        const int kk = k0 + i * 64;
        const bool more = (i + 1 < 20);
        uint4 u[8]; float wg[4];
        if (more) {
            corners(kk + 64, dyN, dxN, u, wg);          // loads issue early
            if (i + 2 < 20) off_load(kk + 128, dyN, dxN);
        }
        mfma_64k(Abase, CK5, kk, Bsl[i & 1], quad, l16, acc);
        if (more) {
            unsigned short* Bn = Bsl[(i + 1) & 1];
            *(uint4*)(&Bn[px * BPAD + seg * 8])      = blend4(u,     wg);
            *(uint4*)(&Bn[px * BPAD + 32 + seg * 8]) = blend4(u + 4, wg);
        }
        __syncthreads();
    }
    epilogue_atomic(Cf, n0, wave, quad, l16, C, acc);
}

extern "C" void kernel_launch(void* const* d_in, const int* in_sizes, int n_in,
                              void* d_out, int out_size, void* d_ws, size_t ws_size,
                              hipStream_t stream) {
    const float* x      = (const float*)d_in[0];
    const float* w_off  = (const float*)d_in[1];
    const float* w_def  = (const float*)d_in[2];
    const float* w_temp = (const float*)d_in[3];
    const float* b_temp = (const float*)d_in[4];
    float* out = (float*)d_out;

    // workspace (~24.2 MB)
    unsigned short* xt   = (unsigned short*)d_ws;                         //  4,718,592
    float*          offb = (float*)((char*)d_ws + 4718592ul);             //  9,437,184
    unsigned short* wbo  = (unsigned short*)((char*)d_ws + 14155776ul);   //  3,276,800
    unsigned short* wbd  = (unsigned short*)((char*)d_ws + 17432576ul);   //  3,276,800
    unsigned short* wbT  = (unsigned short*)((char*)d_ws + 20709376ul);   //  3,538,944

    prep_k<<<24320, 256, 0, stream>>>(w_off, w_def, w_temp, b_temp, wbo, wbd, wbT, offb, out);
    xt_k<<<dim3(36, 4, T), 256, 0, stream>>>(x, xt);
    gemm_ot_k<<<dim3(144, 1, 11), 256, 0, stream>>>(wbo, wbT, xt, offb, out);
    gemm_def_k<<<dim3(144, 1, 5), 256, 0, stream>>>(wbd, xt, offb, out);
}

// Round 8
// 303.600 us; speedup vs baseline: 1.2955x; 1.2955x over previous
//
#include <hip/hip_runtime.h>
#include <hip/hip_bf16.h>

#define T    4
#define C    256
#define H    48
#define W    48
#define HW   2304
#define OFFC 200
#define CK5  6400      // offset/deform K, (q,c) c-inner
#define CK9  2304      // temporal per-tap K, (j,c) c-inner
#define NFULL 9216     // T*HW
#define BPAD 72        // B LDS row pitch (shorts)

typedef __attribute__((ext_vector_type(8))) short bf16x8;
typedef __attribute__((ext_vector_type(4))) float f32x4;

__device__ __forceinline__ unsigned short f2bf(float f) {
    unsigned int u = __float_as_uint(f);
    return (unsigned short)((u + 0x7FFFu + ((u >> 16) & 1u)) >> 16);
}
__device__ __forceinline__ float bflo(unsigned int v) { return __uint_as_float(v << 16); }
__device__ __forceinline__ float bfhi(unsigned int v) { return __uint_as_float(v & 0xFFFF0000u); }
__device__ __forceinline__ unsigned int pack2(float lo, float hi) {
    __hip_bfloat162 h = __float22bfloat162_rn(make_float2(lo, hi));
    return *reinterpret_cast<unsigned int*>(&h);
}
__device__ __forceinline__ void gload16(const void* g, void* l) {
    __builtin_amdgcn_global_load_lds(
        (const __attribute__((address_space(1))) unsigned int*)g,
        (__attribute__((address_space(3))) unsigned int*)l, 16, 0, 0);
}

// ---------------------------------------------------------------------------
// prep: all weight casts + offb zero + out bias-fill in ONE launch.
// ---------------------------------------------------------------------------
__global__ __launch_bounds__(256) void prep_k(const float* __restrict__ w_off,
                                              const float* __restrict__ w_def,
                                              const float* __restrict__ w_temp,
                                              const float* __restrict__ bias,
                                              unsigned short* __restrict__ wbo,
                                              unsigned short* __restrict__ wbd,
                                              unsigned short* __restrict__ wbT,
                                              float* __restrict__ offb,
                                              float* __restrict__ out) {
    long i = (long)blockIdx.x * 256 + threadIdx.x;
    if (i < 1638400) {                       // w_off -> wbo (M padded to 256)
        const int c = (int)(i & 255); const int rest = (int)(i >> 8);
        const int q = rest % 25, o = rest / 25;
        wbo[(long)o * CK5 + q * 256 + c] =
            (o < OFFC) ? f2bf(w_off[((long)o * 256 + c) * 25 + q]) : (unsigned short)0;
    } else if (i < 3276800) {                // w_def -> wbd
        i -= 1638400;
        const int c = (int)(i & 255); const int rest = (int)(i >> 8);
        const int q = rest % 25, o = rest / 25;
        wbd[(long)o * CK5 + q * 256 + c] = f2bf(w_def[((long)o * 256 + c) * 25 + q]);
    } else if (i < 5046272) {                // w_temp -> wbT[kt][o][(j,c)]
        i -= 3276800;
        const int c = (int)(i & 255); const int rest = (int)(i >> 8);
        const int j = rest % 9, oo = rest / 9;
        const int o = oo & 255, kt = oo >> 8;
        wbT[(long)kt * (256 * CK9) + (long)o * CK9 + j * 256 + c] =
            f2bf(w_temp[((long)o * 256 + c) * 27 + kt * 9 + j]);
    } else if (i < 5636096) {                // zero offb
        i -= 5046272;
        ((float4*)offb)[i] = make_float4(0.f, 0.f, 0.f, 0.f);
    } else {                                 // out = bias
        i -= 5636096;
        const float b = bias[(int)(i / 2304)];
        ((float4*)out)[i] = make_float4(b, b, b, b);
    }
}

// ---------------------------------------------------------------------------
// x[c][t][p] fp32 -> xt[t][p][c] bf16 via LDS transpose. grid (36, 4 ct, T)
// ---------------------------------------------------------------------------
__global__ __launch_bounds__(256) void xt_k(const float* __restrict__ x,
                                            unsigned short* __restrict__ xt) {
    __shared__ float tile[64][65];
    const int p0 = blockIdx.x * 64, c0 = blockIdx.y * 64, t = blockIdx.z;
    const int px = threadIdx.x & 63, sub = threadIdx.x >> 6;
    for (int cl = sub; cl < 64; cl += 4)
        tile[px][cl] = x[((long)(c0 + cl) * T + t) * HW + p0 + px];
    __syncthreads();
    const int seg = sub * 16;
    unsigned int pk[8];
    #pragma unroll
    for (int d = 0; d < 8; ++d)
        pk[d] = pack2(tile[px][seg + d * 2], tile[px][seg + d * 2 + 1]);
    unsigned short* orow = xt + ((long)t * HW + p0 + px) * 256 + c0 + seg;
    *(uint4*)(orow + 0) = make_uint4(pk[0], pk[1], pk[2], pk[3]);
    *(uint4*)(orow + 8) = make_uint4(pk[4], pk[5], pk[6], pk[7]);
}

// ---------------------------------------------------------------------------
// MFMA core, BM=128, BN=64, BK=64.
// A LDS: 128 rows x 64 shorts, slot-swizzled (row r, slot s holds global
//   16B-chunk (s - (r&7)) & 7); staged with 4 gload16/lane per iter.
// B LDS: 64 rows x BPAD(72) shorts.
// Wave grid: wm=(wave&1)*64, wn=(wave>>1)*32; acc[4][2]; 16 MFMA/iter.
// ---------------------------------------------------------------------------
__device__ __forceinline__ void mfma_iter(const unsigned short* __restrict__ Asl,
                                          const unsigned short* __restrict__ Bsl,
                                          int wave, int quad, int l16, f32x4 acc[4][2]) {
    const int wm = (wave & 1) * 64, wn = (wave >> 1) * 32;
    #pragma unroll
    for (int kh = 0; kh < 2; ++kh) {
        bf16x8 af[4], bfr[2];
        #pragma unroll
        for (int i = 0; i < 4; ++i) {
            const int row = wm + i * 16 + l16;
            const int slot = (kh * 4 + quad + (l16 & 7)) & 7;
            af[i] = *(const bf16x8*)(Asl + row * 64 + slot * 8);
        }
        #pragma unroll
        for (int j = 0; j < 2; ++j)
            bfr[j] = *(const bf16x8*)(Bsl + (wn + j * 16 + l16) * BPAD + kh * 32 + quad * 8);
        #pragma unroll
        for (int i = 0; i < 4; ++i)
            #pragma unroll
            for (int j = 0; j < 2; ++j)
                acc[i][j] = __builtin_amdgcn_mfma_f32_16x16x32_bf16(af[i], bfr[j], acc[i][j], 0, 0, 0);
    }
}
__device__ __forceinline__ void epilogue_atomic(float* __restrict__ Cf, int m0, int n0,
                                                int wave, int quad, int l16,
                                                int Mvalid, f32x4 acc[4][2]) {
    const int wm = (wave & 1) * 64, wn = (wave >> 1) * 32;
    #pragma unroll
    for (int i = 0; i < 4; ++i)
        #pragma unroll
        for (int rr = 0; rr < 4; ++rr) {
            const int o = m0 + wm + i * 16 + quad * 4 + rr;
            if (o >= Mvalid) continue;
            #pragma unroll
            for (int j = 0; j < 2; ++j)
                unsafeAtomicAdd(Cf + (long)o * NFULL + n0 + wn + j * 16 + l16, acc[i][j][rr]);
        }
}

// ---------------------------------------------------------------------------
// Shift-window GEMM body (offset conv mode 0: 5x5 pad2; temporal mode 1:
// 3x3 pad1).  Two barriers/iter; window loads for i+1 issued in the compute
// section (not drained by the staging barrier).
// ---------------------------------------------------------------------------
__device__ __forceinline__ void gemm_shift_body(unsigned short* __restrict__ Asl,
                                                unsigned short* __restrict__ Bsl,
                                                const unsigned short* __restrict__ A, long ldA,
                                                const unsigned short* __restrict__ xt, int tsrc,
                                                float* __restrict__ Cf, int Mvalid,
                                                int m0, int n0, int k0, int iters, int mode) {
    const int tid = threadIdx.x;
    const int wave = tid >> 6, lane = tid & 63;
    const int quad = lane >> 4, l16 = lane & 15;
    const int t = n0 / HW, p0 = n0 - t * HW;
    const int px = tid >> 2, seg = tid & 3;
    const int p = p0 + px, h = p / 48, w = p - h * 48;
    const unsigned short* xts = xt + (long)tsrc * HW * 256 + seg * 8;

    const int r8 = lane >> 3, s8 = lane & 7;
    const int qg = (s8 - r8) & 7;              // A slot swizzle
    const long ldAb = ldA * 2;
    const char* Ap = (const char*)A + (long)(m0 + wave * 32 + r8) * ldAb
                     + (long)k0 * 2 + qg * 16;
    const long rstep8 = 8 * ldAb;
    unsigned short* la = Asl + wave * 2048;

    auto produce = [&](int kk, uint4& v0, uint4& v1) {
        const int q = kk >> 8, cb = kk & 255;
        int qy, qx;
        if (mode == 0) { const int d = q / 5; qy = d - 2; qx = q - d * 5 - 2; }
        else           { const int d = q / 3; qy = d - 1; qx = q - d * 3 - 1; }
        const int y = h + qy, xx = w + qx;
        v0 = make_uint4(0u, 0u, 0u, 0u); v1 = v0;
        if ((y >= 0) & (y < 48) & (xx >= 0) & (xx < 48)) {
            const unsigned short* bp = xts + (y * 48 + xx) * 256 + cb;
            v0 = *(const uint4*)bp; v1 = *(const uint4*)(bp + 32);
        }
    };

    uint4 cv0, cv1;
    produce(k0, cv0, cv1);

    f32x4 acc[4][2] = {};
    for (int i = 0; i < iters; ++i) {
        __syncthreads();
        #pragma unroll
        for (int c2 = 0; c2 < 4; ++c2) gload16(Ap + c2 * rstep8, la + c2 * 512);
        Ap += 128;
        *(uint4*)(Bsl + px * BPAD + seg * 8)      = cv0;
        *(uint4*)(Bsl + px * BPAD + 32 + seg * 8) = cv1;
        __syncthreads();
        if (i + 1 < iters) produce(k0 + (i + 1) * 64, cv0, cv1);  // issue early
        mfma_iter(Asl, Bsl, wave, quad, l16, acc);
    }
    epilogue_atomic(Cf, m0, n0, wave, quad, l16, Mvalid, acc);
}

// offset (z 0..3, split-K 4) + temporal (z 4..9 = tap*2+half) in ONE launch.
// grid (144, 2, 10).
__global__ __launch_bounds__(256, 4) void gemm_ot_k(const unsigned short* __restrict__ wbo,
                                                    const unsigned short* __restrict__ wbT,
                                                    const unsigned short* __restrict__ xt,
                                                    float* __restrict__ offb,
                                                    float* __restrict__ out) {
    __shared__ unsigned short Asl[128 * 64];
    __shared__ unsigned short Bsl[64 * BPAD];
    const int z = blockIdx.z, n0 = blockIdx.x * 64, m0 = blockIdx.y * 128;
    const int t = n0 / HW;
    if (z < 4) {
        gemm_shift_body(Asl, Bsl, wbo, CK5, xt, t, offb, OFFC, m0, n0, z * 1600, 25, 0);
    } else {
        const int zz = z - 4, kt = zz >> 1, half = zz & 1;
        const int tsrc = t + kt - 1;
        if (tsrc < 0 || tsrc >= T) return;
        gemm_shift_body(Asl, Bsl, wbT + (long)kt * 256 * CK9, CK9, xt, tsrc, out, C,
                        m0, n0, half * 1152, 18, 1);
    }
}

// ---------------------------------------------------------------------------
// Deformable GEMM.  grid (144, 2, 4): split-K 4 (kLen 1600, 25 iters).
// Corner loads for i+1 issued after the staging barrier, blended after MFMA.
// ---------------------------------------------------------------------------
__device__ __forceinline__ void pos_calc(int h, int w, int q, float dy, float dx,
                                         float wgt[4], int idx[4]) {
    const int d = q / 5;
    const int qy = d - 2, qx = q - d * 5 - 2;
    const float sy = (float)(h + qy) + dy;
    const float sx = (float)(w + qx) + dx;
    const float y0f = floorf(sy), x0f = floorf(sx);
    const float wy = sy - y0f, wx = sx - x0f;
    const int y0 = (int)y0f, x0 = (int)x0f;
    const int y1 = y0 + 1, x1 = x0 + 1;
    float w00 = (1.f - wy) * (1.f - wx);
    float w01 = (1.f - wy) * wx;
    float w10 = wy * (1.f - wx);
    float w11 = wy * wx;
    const bool vy0 = (y0 >= 0) & (y0 < 48), vy1 = (y1 >= 0) & (y1 < 48);
    const bool vx0 = (x0 >= 0) & (x0 < 48), vx1 = (x1 >= 0) & (x1 < 48);
    if (!(vy0 & vx0)) w00 = 0.f;
    if (!(vy0 & vx1)) w01 = 0.f;
    if (!(vy1 & vx0)) w10 = 0.f;
    if (!(vy1 & vx1)) w11 = 0.f;
    const int yc0 = min(max(y0, 0), 47), yc1 = min(max(y1, 0), 47);
    const int xc0 = min(max(x0, 0), 47), xc1 = min(max(x1, 0), 47);
    wgt[0] = w00; wgt[1] = w01; wgt[2] = w10; wgt[3] = w11;
    idx[0] = yc0 * 48 + xc0; idx[1] = yc0 * 48 + xc1;
    idx[2] = yc1 * 48 + xc0; idx[3] = yc1 * 48 + xc1;
}
__device__ __forceinline__ uint4 blend4(const uint4 u[4], const float wgt[4]) {
    unsigned int pk[4];
    #pragma unroll
    for (int qi = 0; qi < 4; ++qi) {
        const unsigned int a = ((const unsigned int*)&u[0])[qi];
        const unsigned int b = ((const unsigned int*)&u[1])[qi];
        const unsigned int c = ((const unsigned int*)&u[2])[qi];
        const unsigned int d = ((const unsigned int*)&u[3])[qi];
        const float rl = wgt[0] * bflo(a) + wgt[1] * bflo(b) + wgt[2] * bflo(c) + wgt[3] * bflo(d);
        const float rh = wgt[0] * bfhi(a) + wgt[1] * bfhi(b) + wgt[2] * bfhi(c) + wgt[3] * bfhi(d);
        pk[qi] = pack2(rl, rh);
    }
    return make_uint4(pk[0], pk[1], pk[2], pk[3]);
}

__global__ __launch_bounds__(256, 4) void gemm_def_k(const unsigned short* __restrict__ A,
                                                     const unsigned short* __restrict__ xt,
                                                     const float* __restrict__ offb,
                                                     float* __restrict__ Cf) {
    __shared__ unsigned short Asl[128 * 64];
    __shared__ unsigned short Bsl[64 * BPAD];
    const int tid = threadIdx.x;
    const int wave = tid >> 6, lane = tid & 63;
    const int quad = lane >> 4, l16 = lane & 15;
    const int n0 = blockIdx.x * 64, m0 = blockIdx.y * 128, k0 = blockIdx.z * 1600;
    const int t = n0 / HW, p0 = n0 - t * HW;
    const int px = tid >> 2, seg = tid & 3;
    const int p = p0 + px, h = p / 48, w = p - h * 48;
    const int nabs = n0 + px;
    const unsigned short* xts = xt + (long)t * HW * 256 + seg * 8;

    const int r8 = lane >> 3, s8 = lane & 7;
    const int qg = (s8 - r8) & 7;
    const long ldAb = (long)CK5 * 2;
    const char* Ap = (const char*)A + (long)(m0 + wave * 32 + r8) * ldAb
                     + (long)k0 * 2 + qg * 16;
    const long rstep8 = 8 * ldAb;
    unsigned short* la = Asl + wave * 2048;

    auto off_load = [&](int kk, float& dy, float& dx) {
        const int q = kk >> 8, g = (kk & 255) >> 6;
        dy = offb[(long)(g * 50 + 2 * q) * NFULL + nabs];
        dx = offb[(long)(g * 50 + 2 * q + 1) * NFULL + nabs];
    };
    auto corners = [&](int kk, float dy, float dx, uint4 u[8], float wgt[4]) {
        const int cb = kk & 255;
        int idx[4];
        pos_calc(h, w, kk >> 8, dy, dx, wgt, idx);
        #pragma unroll
        for (int cn = 0; cn < 4; ++cn) {
            const unsigned short* bp = xts + idx[cn] * 256 + cb;
            u[cn]     = *(const uint4*)bp;
            u[cn + 4] = *(const uint4*)(bp + 32);
        }
    };

    uint4 pkv0, pkv1;
    float dyN, dxN;
    {
        float dy0, dx0;
        off_load(k0, dy0, dx0);
        uint4 u[8]; float wg[4];
        corners(k0, dy0, dx0, u, wg);
        pkv0 = blend4(u, wg);
        pkv1 = blend4(u + 4, wg);
        off_load(k0 + 64, dyN, dxN);
    }

    f32x4 acc[4][2] = {};
    for (int i = 0; i < 25; ++i) {
        const int kk = k0 + i * 64;
        __syncthreads();
        #pragma unroll
        for (int c2 = 0; c2 < 4; ++c2) gload16(Ap + c2 * rstep8, la + c2 * 512);
        Ap += 128;
        *(uint4*)(Bsl + px * BPAD + seg * 8)      = pkv0;
        *(uint4*)(Bsl + px * BPAD + 32 + seg * 8) = pkv1;
        __syncthreads();
        const bool more = (i + 1 < 25);
        uint4 u[8]; float wg[4];
        if (more) {
            corners(kk + 64, dyN, dxN, u, wg);        // loads issue here,
            if (i + 2 < 25) off_load(kk + 128, dyN, dxN);   // waited after MFMA
        }
        mfma_iter(Asl, Bsl, wave, quad, l16, acc);
        if (more) {
            pkv0 = blend4(u, wg);
            pkv1 = blend4(u + 4, wg);
        }
    }
    epilogue_atomic(Cf, m0, n0, wave, quad, l16, C, acc);
}

extern "C" void kernel_launch(void* const* d_in, const int* in_sizes, int n_in,
                              void* d_out, int out_size, void* d_ws, size_t ws_size,
                              hipStream_t stream) {
    const float* x      = (const float*)d_in[0];
    const float* w_off  = (const float*)d_in[1];
    const float* w_def  = (const float*)d_in[2];
    const float* w_temp = (const float*)d_in[3];
    const float* b_temp = (const float*)d_in[4];
    float* out = (float*)d_out;

    // workspace (~24.2 MB)
    unsigned short* xt   = (unsigned short*)d_ws;                         //  4,718,592
    float*          offb = (float*)((char*)d_ws + 4718592ul);             //  9,437,184
    unsigned short* wbo  = (unsigned short*)((char*)d_ws + 14155776ul);   //  3,276,800
    unsigned short* wbd  = (unsigned short*)((char*)d_ws + 17432576ul);   //  3,276,800
    unsigned short* wbT  = (unsigned short*)((char*)d_ws + 20709376ul);   //  3,538,944

    prep_k<<<24320, 256, 0, stream>>>(w_off, w_def, w_temp, b_temp, wbo, wbd, wbT, offb, out);
    xt_k<<<dim3(36, 4, T), 256, 0, stream>>>(x, xt);
    gemm_ot_k<<<dim3(144, 2, 10), 256, 0, stream>>>(wbo, wbT, xt, offb, out);
    gemm_def_k<<<dim3(144, 2, 4), 256, 0, stream>>>(wbd, xt, offb, out);
}

// Round 9
// 289.326 us; speedup vs baseline: 1.3594x; 1.0493x over previous
//
#include <hip/hip_runtime.h>
#include <hip/hip_bf16.h>

#define T    4
#define C    256
#define H    48
#define W    48
#define HW   2304
#define OFFC 200
#define CK5  6400      // offset/deform K, (q,c) c-inner
#define CK9  2304      // temporal per-tap K, (j,c) c-inner
#define NFULL 9216     // T*HW
#define BPAD 72        // B LDS row pitch (shorts)

typedef __attribute__((ext_vector_type(8))) short bf16x8;
typedef __attribute__((ext_vector_type(4))) float f32x4;

__device__ __forceinline__ unsigned short f2bf(float f) {
    unsigned int u = __float_as_uint(f);
    return (unsigned short)((u + 0x7FFFu + ((u >> 16) & 1u)) >> 16);
}
__device__ __forceinline__ float bflo(unsigned int v) { return __uint_as_float(v << 16); }
__device__ __forceinline__ float bfhi(unsigned int v) { return __uint_as_float(v & 0xFFFF0000u); }
__device__ __forceinline__ unsigned int pack2(float lo, float hi) {
    __hip_bfloat162 h = __float22bfloat162_rn(make_float2(lo, hi));
    return *reinterpret_cast<unsigned int*>(&h);
}
__device__ __forceinline__ void gload16(const void* g, void* l) {
    __builtin_amdgcn_global_load_lds(
        (const __attribute__((address_space(1))) unsigned int*)g,
        (__attribute__((address_space(3))) unsigned int*)l, 16, 0, 0);
}

// ---------------------------------------------------------------------------
// prep + xt transpose merged: blocks [0, 24320) do casts/fills, [24320, 24896)
// do the x -> xt[t][p][c] bf16 transpose.
// ---------------------------------------------------------------------------
__global__ __launch_bounds__(256) void prep_xt_k(const float* __restrict__ x,
                                                 const float* __restrict__ w_off,
                                                 const float* __restrict__ w_def,
                                                 const float* __restrict__ w_temp,
                                                 const float* __restrict__ bias,
                                                 unsigned short* __restrict__ wbo,
                                                 unsigned short* __restrict__ wbd,
                                                 unsigned short* __restrict__ wbT,
                                                 float* __restrict__ offb,
                                                 float* __restrict__ out,
                                                 unsigned short* __restrict__ xt) {
    __shared__ float tile[64][65];
    if (blockIdx.x >= 24320) {                   // ---- xt transpose path ----
        const int zb = blockIdx.x - 24320;       // 0..575
        const int p0 = (zb % 36) * 64, c0 = ((zb / 36) & 3) * 64, t = zb / 144;
        const int px = threadIdx.x & 63, sub = threadIdx.x >> 6;
        for (int cl = sub; cl < 64; cl += 4)
            tile[px][cl] = x[((long)(c0 + cl) * T + t) * HW + p0 + px];
        __syncthreads();
        const int seg = sub * 16;
        unsigned int pk[8];
        #pragma unroll
        for (int d = 0; d < 8; ++d)
            pk[d] = pack2(tile[px][seg + d * 2], tile[px][seg + d * 2 + 1]);
        unsigned short* orow = xt + ((long)t * HW + p0 + px) * 256 + c0 + seg;
        *(uint4*)(orow + 0) = make_uint4(pk[0], pk[1], pk[2], pk[3]);
        *(uint4*)(orow + 8) = make_uint4(pk[4], pk[5], pk[6], pk[7]);
        return;
    }
    long i = (long)blockIdx.x * 256 + threadIdx.x;
    if (i < 1638400) {                       // w_off -> wbo (M padded to 256)
        const int c = (int)(i & 255); const int rest = (int)(i >> 8);
        const int q = rest % 25, o = rest / 25;
        wbo[(long)o * CK5 + q * 256 + c] =
            (o < OFFC) ? f2bf(w_off[((long)o * 256 + c) * 25 + q]) : (unsigned short)0;
    } else if (i < 3276800) {                // w_def -> wbd
        i -= 1638400;
        const int c = (int)(i & 255); const int rest = (int)(i >> 8);
        const int q = rest % 25, o = rest / 25;
        wbd[(long)o * CK5 + q * 256 + c] = f2bf(w_def[((long)o * 256 + c) * 25 + q]);
    } else if (i < 5046272) {                // w_temp -> wbT[kt][o][(j,c)]
        i -= 3276800;
        const int c = (int)(i & 255); const int rest = (int)(i >> 8);
        const int j = rest % 9, oo = rest / 9;
        const int o = oo & 255, kt = oo >> 8;
        wbT[(long)kt * (256 * CK9) + (long)o * CK9 + j * 256 + c] =
            f2bf(w_temp[((long)o * 256 + c) * 27 + kt * 9 + j]);
    } else if (i < 5636096) {                // zero offb
        i -= 5046272;
        ((float4*)offb)[i] = make_float4(0.f, 0.f, 0.f, 0.f);
    } else {                                 // out = bias
        i -= 5636096;
        const float b = bias[(int)(i / 2304)];
        ((float4*)out)[i] = make_float4(b, b, b, b);
    }
}

// ===========================================================================
// BN=64 MFMA core (BM=128, BK=64) — used by def + temporal.
// A LDS slot-swizzled; B LDS pitch BPAD.
// ===========================================================================
__device__ __forceinline__ void mfma_iter(const unsigned short* __restrict__ Asl,
                                          const unsigned short* __restrict__ Bsl,
                                          int wave, int quad, int l16, f32x4 acc[4][2]) {
    const int wm = (wave & 1) * 64, wn = (wave >> 1) * 32;
    #pragma unroll
    for (int kh = 0; kh < 2; ++kh) {
        bf16x8 af[4], bfr[2];
        #pragma unroll
        for (int i = 0; i < 4; ++i) {
            const int row = wm + i * 16 + l16;
            const int slot = (kh * 4 + quad + (l16 & 7)) & 7;
            af[i] = *(const bf16x8*)(Asl + row * 64 + slot * 8);
        }
        #pragma unroll
        for (int j = 0; j < 2; ++j)
            bfr[j] = *(const bf16x8*)(Bsl + (wn + j * 16 + l16) * BPAD + kh * 32 + quad * 8);
        #pragma unroll
        for (int i = 0; i < 4; ++i)
            #pragma unroll
            for (int j = 0; j < 2; ++j)
                acc[i][j] = __builtin_amdgcn_mfma_f32_16x16x32_bf16(af[i], bfr[j], acc[i][j], 0, 0, 0);
    }
}
__device__ __forceinline__ void epilogue_atomic(float* __restrict__ Cf, int m0, int n0,
                                                int wave, int quad, int l16,
                                                int Mvalid, f32x4 acc[4][2]) {
    const int wm = (wave & 1) * 64, wn = (wave >> 1) * 32;
    #pragma unroll
    for (int i = 0; i < 4; ++i)
        #pragma unroll
        for (int rr = 0; rr < 4; ++rr) {
            const int o = m0 + wm + i * 16 + quad * 4 + rr;
            if (o >= Mvalid) continue;
            #pragma unroll
            for (int j = 0; j < 2; ++j)
                unsafeAtomicAdd(Cf + (long)o * NFULL + n0 + wn + j * 16 + l16, acc[i][j][rr]);
        }
}

// ===========================================================================
// Offset GEMM, BN=128 (BM=128, BK=64): 32 MFMA per barrier pair, half the
// A-operand L3 re-reads of the BN=64 version.  grid (72, 2, 5).
// ===========================================================================
__global__ __launch_bounds__(256, 4) void gemm_off_k(const unsigned short* __restrict__ A,
                                                     const unsigned short* __restrict__ xt,
                                                     float* __restrict__ Cf) {
    __shared__ unsigned short Asl[128 * 64];
    __shared__ unsigned short Bsl[128 * BPAD];
    const int tid = threadIdx.x;
    const int wave = tid >> 6, lane = tid & 63;
    const int quad = lane >> 4, l16 = lane & 15;
    const int n0 = blockIdx.x * 128, m0 = blockIdx.y * 128, k0 = blockIdx.z * 1280;
    const int t = n0 / HW, p0 = n0 - t * HW;
    const int wm = (wave & 1) * 64, wn = (wave >> 1) * 64;

    const int r8 = lane >> 3, s8 = lane & 7;
    const int qg = (s8 - r8) & 7;              // A slot swizzle
    const long ldAb = (long)CK5 * 2;
    const char* Ap = (const char*)A + (long)(m0 + wave * 32 + r8) * ldAb
                     + (long)k0 * 2 + qg * 16;
    const long rstep8 = 8 * ldAb;
    unsigned short* la = Asl + wave * 2048;

    const int px = tid >> 1, half = tid & 1;
    const int p = p0 + px, h = p / 48, w = p - h * 48;
    const unsigned short* xts = xt + (long)t * HW * 256 + half * 32;

    auto produce = [&](int kk, uint4 v[4]) {
        const int q = kk >> 8, cb = kk & 255;
        const int d = q / 5;
        const int y = h + d - 2, xx = w + (q - d * 5) - 2;
        v[0] = make_uint4(0u, 0u, 0u, 0u); v[1] = v[0]; v[2] = v[0]; v[3] = v[0];
        if ((y >= 0) & (y < 48) & (xx >= 0) & (xx < 48)) {
            const unsigned short* bp = xts + (y * 48 + xx) * 256 + cb;
            #pragma unroll
            for (int d4 = 0; d4 < 4; ++d4) v[d4] = *(const uint4*)(bp + d4 * 8);
        }
    };

    uint4 cv[4];
    produce(k0, cv);

    f32x4 acc[4][4] = {};
    for (int i = 0; i < 20; ++i) {
        __syncthreads();
        #pragma unroll
        for (int c2 = 0; c2 < 4; ++c2) gload16(Ap + c2 * rstep8, la + c2 * 512);
        Ap += 128;
        #pragma unroll
        for (int d4 = 0; d4 < 4; ++d4)
            *(uint4*)(Bsl + px * BPAD + half * 32 + d4 * 8) = cv[d4];
        __syncthreads();
        if (i + 1 < 20) produce(k0 + (i + 1) * 64, cv);   // issue early
        #pragma unroll
        for (int kh = 0; kh < 2; ++kh) {
            bf16x8 af[4], bfr[4];
            #pragma unroll
            for (int ii = 0; ii < 4; ++ii) {
                const int row = wm + ii * 16 + l16;
                const int slot = (kh * 4 + quad + (l16 & 7)) & 7;
                af[ii] = *(const bf16x8*)(Asl + row * 64 + slot * 8);
            }
            #pragma unroll
            for (int j = 0; j < 4; ++j)
                bfr[j] = *(const bf16x8*)(Bsl + (wn + j * 16 + l16) * BPAD + kh * 32 + quad * 8);
            #pragma unroll
            for (int ii = 0; ii < 4; ++ii)
                #pragma unroll
                for (int j = 0; j < 4; ++j)
                    acc[ii][j] = __builtin_amdgcn_mfma_f32_16x16x32_bf16(af[ii], bfr[j], acc[ii][j], 0, 0, 0);
        }
    }
    #pragma unroll
    for (int i = 0; i < 4; ++i)
        #pragma unroll
        for (int rr = 0; rr < 4; ++rr) {
            const int o = m0 + wm + i * 16 + quad * 4 + rr;
            if (o >= OFFC) continue;
            #pragma unroll
            for (int j = 0; j < 4; ++j)
                unsafeAtomicAdd(Cf + (long)o * NFULL + n0 + wn + j * 16 + l16, acc[i][j][rr]);
        }
}

// ===========================================================================
// def + temporal merged launch (both BN=64, R8-proven bodies).
// grid (144, 2, 10): z 0..3 = deform split-K; z 4..9 = temporal tap*2+half.
// ===========================================================================
__device__ __forceinline__ void pos_calc(int h, int w, int q, float dy, float dx,
                                         float wgt[4], int idx[4]) {
    const int d = q / 5;
    const int qy = d - 2, qx = q - d * 5 - 2;
    const float sy = (float)(h + qy) + dy;
    const float sx = (float)(w + qx) + dx;
    const float y0f = floorf(sy), x0f = floorf(sx);
    const float wy = sy - y0f, wx = sx - x0f;
    const int y0 = (int)y0f, x0 = (int)x0f;
    const int y1 = y0 + 1, x1 = x0 + 1;
    float w00 = (1.f - wy) * (1.f - wx);
    float w01 = (1.f - wy) * wx;
    float w10 = wy * (1.f - wx);
    float w11 = wy * wx;
    const bool vy0 = (y0 >= 0) & (y0 < 48), vy1 = (y1 >= 0) & (y1 < 48);
    const bool vx0 = (x0 >= 0) & (x0 < 48), vx1 = (x1 >= 0) & (x1 < 48);
    if (!(vy0 & vx0)) w00 = 0.f;
    if (!(vy0 & vx1)) w01 = 0.f;
    if (!(vy1 & vx0)) w10 = 0.f;
    if (!(vy1 & vx1)) w11 = 0.f;
    const int yc0 = min(max(y0, 0), 47), yc1 = min(max(y1, 0), 47);
    const int xc0 = min(max(x0, 0), 47), xc1 = min(max(x1, 0), 47);
    wgt[0] = w00; wgt[1] = w01; wgt[2] = w10; wgt[3] = w11;
    idx[0] = yc0 * 48 + xc0; idx[1] = yc0 * 48 + xc1;
    idx[2] = yc1 * 48 + xc0; idx[3] = yc1 * 48 + xc1;
}
__device__ __forceinline__ uint4 blend4(const uint4 u[4], const float wgt[4]) {
    unsigned int pk[4];
    #pragma unroll
    for (int qi = 0; qi < 4; ++qi) {
        const unsigned int a = ((const unsigned int*)&u[0])[qi];
        const unsigned int b = ((const unsigned int*)&u[1])[qi];
        const unsigned int c = ((const unsigned int*)&u[2])[qi];
        const unsigned int d = ((const unsigned int*)&u[3])[qi];
        const float rl = wgt[0] * bflo(a) + wgt[1] * bflo(b) + wgt[2] * bflo(c) + wgt[3] * bflo(d);
        const float rh = wgt[0] * bfhi(a) + wgt[1] * bfhi(b) + wgt[2] * bfhi(c) + wgt[3] * bfhi(d);
        pk[qi] = pack2(rl, rh);
    }
    return make_uint4(pk[0], pk[1], pk[2], pk[3]);
}

__device__ __forceinline__ void gemm_def_body(unsigned short* __restrict__ Asl,
                                              unsigned short* __restrict__ Bsl,
                                              const unsigned short* __restrict__ A,
                                              const unsigned short* __restrict__ xt,
                                              const float* __restrict__ offb,
                                              float* __restrict__ Cf,
                                              int m0, int n0, int k0) {
    const int tid = threadIdx.x;
    const int wave = tid >> 6, lane = tid & 63;
    const int quad = lane >> 4, l16 = lane & 15;
    const int t = n0 / HW, p0 = n0 - t * HW;
    const int px = tid >> 2, seg = tid & 3;
    const int p = p0 + px, h = p / 48, w = p - h * 48;
    const int nabs = n0 + px;
    const unsigned short* xts = xt + (long)t * HW * 256 + seg * 8;

    const int r8 = lane >> 3, s8 = lane & 7;
    const int qg = (s8 - r8) & 7;
    const long ldAb = (long)CK5 * 2;
    const char* Ap = (const char*)A + (long)(m0 + wave * 32 + r8) * ldAb
                     + (long)k0 * 2 + qg * 16;
    const long rstep8 = 8 * ldAb;
    unsigned short* la = Asl + wave * 2048;

    auto off_load = [&](int kk, float& dy, float& dx) {
        const int q = kk >> 8, g = (kk & 255) >> 6;
        dy = offb[(long)(g * 50 + 2 * q) * NFULL + nabs];
        dx = offb[(long)(g * 50 + 2 * q + 1) * NFULL + nabs];
    };
    auto corners = [&](int kk, float dy, float dx, uint4 u[8], float wgt[4]) {
        const int cb = kk & 255;
        int idx[4];
        pos_calc(h, w, kk >> 8, dy, dx, wgt, idx);
        #pragma unroll
        for (int cn = 0; cn < 4; ++cn) {
            const unsigned short* bp = xts + idx[cn] * 256 + cb;
            u[cn]     = *(const uint4*)bp;
            u[cn + 4] = *(const uint4*)(bp + 32);
        }
    };

    uint4 pkv0, pkv1;
    float dyN, dxN;
    {
        float dy0, dx0;
        off_load(k0, dy0, dx0);
        uint4 u[8]; float wg[4];
        corners(k0, dy0, dx0, u, wg);
        pkv0 = blend4(u, wg);
        pkv1 = blend4(u + 4, wg);
        off_load(k0 + 64, dyN, dxN);
    }

    f32x4 acc[4][2] = {};
    for (int i = 0; i < 25; ++i) {
        const int kk = k0 + i * 64;
        __syncthreads();
        #pragma unroll
        for (int c2 = 0; c2 < 4; ++c2) gload16(Ap + c2 * rstep8, la + c2 * 512);
        Ap += 128;
        *(uint4*)(Bsl + px * BPAD + seg * 8)      = pkv0;
        *(uint4*)(Bsl + px * BPAD + 32 + seg * 8) = pkv1;
        __syncthreads();
        const bool more = (i + 1 < 25);
        uint4 u[8]; float wg[4];
        if (more) {
            corners(kk + 64, dyN, dxN, u, wg);            // loads issue here,
            if (i + 2 < 25) off_load(kk + 128, dyN, dxN); // waited after MFMA
        }
        mfma_iter(Asl, Bsl, wave, quad, l16, acc);
        if (more) {
            pkv0 = blend4(u, wg);
            pkv1 = blend4(u + 4, wg);
        }
    }
    epilogue_atomic(Cf, m0, n0, wave, quad, l16, C, acc);
}

__device__ __forceinline__ void gemm_temp_body(unsigned short* __restrict__ Asl,
                                               unsigned short* __restrict__ Bsl,
                                               const unsigned short* __restrict__ A,
                                               const unsigned short* __restrict__ xt, int tsrc,
                                               float* __restrict__ Cf,
                                               int m0, int n0, int k0) {
    const int tid = threadIdx.x;
    const int wave = tid >> 6, lane = tid & 63;
    const int quad = lane >> 4, l16 = lane & 15;
    const int t = n0 / HW, p0 = n0 - t * HW;
    const int px = tid >> 2, seg = tid & 3;
    const int p = p0 + px, h = p / 48, w = p - h * 48;
    const unsigned short* xts = xt + (long)tsrc * HW * 256 + seg * 8;

    const int r8 = lane >> 3, s8 = lane & 7;
    const int qg = (s8 - r8) & 7;
    const long ldAb = (long)CK9 * 2;
    const char* Ap = (const char*)A + (long)(m0 + wave * 32 + r8) * ldAb
                     + (long)k0 * 2 + qg * 16;
    const long rstep8 = 8 * ldAb;
    unsigned short* la = Asl + wave * 2048;

    auto produce = [&](int kk, uint4& v0, uint4& v1) {
        const int q = kk >> 8, cb = kk & 255;
        const int d = q / 3;
        const int y = h + d - 1, xx = w + (q - d * 3) - 1;
        v0 = make_uint4(0u, 0u, 0u, 0u); v1 = v0;
        if ((y >= 0) & (y < 48) & (xx >= 0) & (xx < 48)) {
            const unsigned short* bp = xts + (y * 48 + xx) * 256 + cb;
            v0 = *(const uint4*)bp; v1 = *(const uint4*)(bp + 32);
        }
    };

    uint4 cv0, cv1;
    produce(k0, cv0, cv1);

    f32x4 acc[4][2] = {};
    for (int i = 0; i < 18; ++i) {
        __syncthreads();
        #pragma unroll
        for (int c2 = 0; c2 < 4; ++c2) gload16(Ap + c2 * rstep8, la + c2 * 512);
        Ap += 128;
        *(uint4*)(Bsl + px * BPAD + seg * 8)      = cv0;
        *(uint4*)(Bsl + px * BPAD + 32 + seg * 8) = cv1;
        __syncthreads();
        if (i + 1 < 18) produce(k0 + (i + 1) * 64, cv0, cv1);  // issue early
        mfma_iter(Asl, Bsl, wave, quad, l16, acc);
    }
    epilogue_atomic(Cf, m0, n0, wave, quad, l16, C, acc);
}

__global__ __launch_bounds__(256, 4) void gemm_dt_k(const unsigned short* __restrict__ wbd,
                                                    const unsigned short* __restrict__ wbT,
                                                    const unsigned short* __restrict__ xt,
                                                    const float* __restrict__ offb,
                                                    float* __restrict__ out) {
    __shared__ unsigned short Asl[128 * 64];
    __shared__ unsigned short Bsl[64 * BPAD];
    const int z = blockIdx.z, n0 = blockIdx.x * 64, m0 = blockIdx.y * 128;
    if (z < 4) {
        gemm_def_body(Asl, Bsl, wbd, xt, offb, out, m0, n0, z * 1600);
    } else {
        const int zz = z - 4, kt = zz >> 1, half = zz & 1;
        const int t = n0 / HW, tsrc = t + kt - 1;
        if (tsrc < 0 || tsrc >= T) return;
        gemm_temp_body(Asl, Bsl, wbT + (long)kt * 256 * CK9, xt, tsrc, out,
                       m0, n0, half * 1152);
    }
}

extern "C" void kernel_launch(void* const* d_in, const int* in_sizes, int n_in,
                              void* d_out, int out_size, void* d_ws, size_t ws_size,
                              hipStream_t stream) {
    const float* x      = (const float*)d_in[0];
    const float* w_off  = (const float*)d_in[1];
    const float* w_def  = (const float*)d_in[2];
    const float* w_temp = (const float*)d_in[3];
    const float* b_temp = (const float*)d_in[4];
    float* out = (float*)d_out;

    // workspace (~24.2 MB)
    unsigned short* xt   = (unsigned short*)d_ws;                         //  4,718,592
    float*          offb = (float*)((char*)d_ws + 4718592ul);             //  9,437,184
    unsigned short* wbo  = (unsigned short*)((char*)d_ws + 14155776ul);   //  3,276,800
    unsigned short* wbd  = (unsigned short*)((char*)d_ws + 17432576ul);   //  3,276,800
    unsigned short* wbT  = (unsigned short*)((char*)d_ws + 20709376ul);   //  3,538,944

    prep_xt_k<<<24896, 256, 0, stream>>>(x, w_off, w_def, w_temp, b_temp,
                                         wbo, wbd, wbT, offb, out, xt);
    gemm_off_k<<<dim3(72, 2, 5), 256, 0, stream>>>(wbo, xt, offb);
    gemm_dt_k<<<dim3(144, 2, 10), 256, 0, stream>>>(wbd, wbT, xt, offb, out);
}